// Round 1
// baseline (268.014 us; speedup 1.0000x reference)
//
#include <hip/hip_runtime.h>
#include <hip/hip_bf16.h>

typedef unsigned short u16;
typedef __bf16 bf16_t;
typedef bf16_t bf16x8 __attribute__((ext_vector_type(8)));
typedef float f32x4 __attribute__((ext_vector_type(4)));

#define MFMA16(a, b, c) __builtin_amdgcn_mfma_f32_16x16x32_bf16((a), (b), (c), 0, 0, 0)

__device__ __forceinline__ u16 f2b(float f) {
  bf16_t h = (bf16_t)f;
  return __builtin_bit_cast(u16, h);
}

__device__ __forceinline__ void gload_lds16(const void* src, void* dst) {
  __builtin_amdgcn_global_load_lds(
      (const __attribute__((address_space(1))) void*)src,
      (__attribute__((address_space(3))) void*)dst, 16, 0, 0);
}

// Read one 16B MFMA fragment from a swizzled LDS tile with 64-bf16 (128B) rows.
// Swizzle: 16B chunk c of row r is stored at chunk c ^ (r & 7).
__device__ __forceinline__ bf16x8 frag_read(const u16* tile, int row, int kchunk) {
  int off = row * 128 + ((kchunk ^ (row & 7)) << 4);
  return *reinterpret_cast<const bf16x8*>(reinterpret_cast<const char*>(tile) + off);
}

// Stage a 128-row x 64-bf16 tile (16KB) global->LDS, pre-swizzled global source
// so LDS dest stays linear (base + lane*16). 4 waves x 4 instrs, 8 rows each.
__device__ __forceinline__ void stage128(const u16* g, int rowStrideElts, u16* tile, int tid) {
  int lane = tid & 63, w = tid >> 6;
#pragma unroll
  for (int i = 0; i < 4; ++i) {
    int r = w * 32 + i * 8 + (lane >> 3);
    int cs = (lane & 7) ^ (r & 7);
    gload_lds16(g + (size_t)r * rowStrideElts + cs * 8, tile + r * 64 + (lane & 7) * 8);
  }
}

// ---------- convert / transpose ----------
__global__ __launch_bounds__(256) void cvt_f32_bf16(const float* __restrict__ in,
                                                    u16* __restrict__ out, int n4) {
  int i = blockIdx.x * 256 + threadIdx.x;
  if (i < n4) {
    float4 f = reinterpret_cast<const float4*>(in)[i];
    ushort4 o;
    o.x = f2b(f.x); o.y = f2b(f.y); o.z = f2b(f.z); o.w = f2b(f.w);
    reinterpret_cast<ushort4*>(out)[i] = o;
  }
}

// in[K][N] f32 -> out[N][K] bf16
__global__ __launch_bounds__(256) void transpose_cvt(const float* __restrict__ in,
                                                     u16* __restrict__ out, int K, int N) {
  __shared__ float t[32][33];
  int n0 = blockIdx.x * 32, k0 = blockIdx.y * 32;
  int tx = threadIdx.x & 31, ty = threadIdx.x >> 5;  // ty in 0..7
#pragma unroll
  for (int i = 0; i < 32; i += 8)
    t[ty + i][tx] = in[(size_t)(k0 + ty + i) * N + n0 + tx];
  __syncthreads();
#pragma unroll
  for (int i = 0; i < 32; i += 8)
    out[(size_t)(n0 + ty + i) * K + k0 + tx] = f2b(t[tx][ty + i]);
}

// ---------- GEMM1: qkv = x @ w_attn + b_attn, routed to q/k/vt ----------
__global__ __launch_bounds__(256) void gemm_qkv(const u16* __restrict__ xb,
                                                const u16* __restrict__ waT,
                                                const float* __restrict__ bias,
                                                u16* __restrict__ q, u16* __restrict__ kk,
                                                u16* __restrict__ vt) {
  __shared__ u16 lA[128 * 64];
  __shared__ u16 lB[128 * 64];
  int tid = threadIdx.x, lane = tid & 63, w = tid >> 6;
  int wr = w >> 1, wc = w & 1;
  int bm = blockIdx.x, bn = blockIdx.y;
  f32x4 acc[4][4] = {};
  const u16* gA = xb + (size_t)bm * 128 * 1024;
  const u16* gB = waT + (size_t)bn * 128 * 1024;
  for (int k0 = 0; k0 < 1024; k0 += 64) {
    stage128(gA + k0, 1024, lA, tid);
    stage128(gB + k0, 1024, lB, tid);
    __syncthreads();
#pragma unroll
    for (int s = 0; s < 2; ++s) {
      bf16x8 af[4], bfr[4];
#pragma unroll
      for (int mi = 0; mi < 4; ++mi)
        af[mi] = frag_read(lA, wr * 64 + mi * 16 + (lane & 15), (lane >> 4) + s * 4);
#pragma unroll
      for (int ni = 0; ni < 4; ++ni)
        bfr[ni] = frag_read(lB, wc * 64 + ni * 16 + (lane & 15), (lane >> 4) + s * 4);
#pragma unroll
      for (int mi = 0; mi < 4; ++mi)
#pragma unroll
        for (int ni = 0; ni < 4; ++ni)
          acc[mi][ni] = MFMA16(af[mi], bfr[ni], acc[mi][ni]);
    }
    __syncthreads();
  }
  int m0 = bm * 128 + wr * 64;
  int n0 = bn * 128 + wc * 64;
#pragma unroll
  for (int ni = 0; ni < 4; ++ni) {
    int col = n0 + ni * 16 + (lane & 15);
    float bv = bias[col];
    int part = col >> 10;
    int cin = col & 1023;
    int h = cin >> 6, d = cin & 63;
#pragma unroll
    for (int mi = 0; mi < 4; ++mi) {
#pragma unroll
      for (int j = 0; j < 4; ++j) {
        int row = m0 + mi * 16 + (lane >> 4) * 4 + j;
        int b = row >> 11, t = row & 2047;
        u16 hv = f2b(acc[mi][ni][j] + bv);
        if (part == 0)
          q[(((size_t)(b * 16 + h) * 2048 + t) << 6) + d] = hv;
        else if (part == 1)
          kk[(((size_t)(b * 16 + h) * 2048 + t) << 6) + d] = hv;
        else
          vt[(((size_t)(b * 16 + h) << 6) + d) * 2048 + t] = hv;  // V pre-transposed [D][T]
      }
    }
  }
}

// ---------- GEMM2: out = att @ w_proj + b_proj (f32 out) ----------
__global__ __launch_bounds__(256) void gemm_proj(const u16* __restrict__ att,
                                                 const u16* __restrict__ wpT,
                                                 const float* __restrict__ bias,
                                                 float* __restrict__ out) {
  __shared__ u16 lA[128 * 64];
  __shared__ u16 lB[128 * 64];
  int tid = threadIdx.x, lane = tid & 63, w = tid >> 6;
  int wr = w >> 1, wc = w & 1;
  int bm = blockIdx.x, bn = blockIdx.y;
  f32x4 acc[4][4] = {};
  const u16* gA = att + (size_t)bm * 128 * 1024;
  const u16* gB = wpT + (size_t)bn * 128 * 1024;
  for (int k0 = 0; k0 < 1024; k0 += 64) {
    stage128(gA + k0, 1024, lA, tid);
    stage128(gB + k0, 1024, lB, tid);
    __syncthreads();
#pragma unroll
    for (int s = 0; s < 2; ++s) {
      bf16x8 af[4], bfr[4];
#pragma unroll
      for (int mi = 0; mi < 4; ++mi)
        af[mi] = frag_read(lA, wr * 64 + mi * 16 + (lane & 15), (lane >> 4) + s * 4);
#pragma unroll
      for (int ni = 0; ni < 4; ++ni)
        bfr[ni] = frag_read(lB, wc * 64 + ni * 16 + (lane & 15), (lane >> 4) + s * 4);
#pragma unroll
      for (int mi = 0; mi < 4; ++mi)
#pragma unroll
        for (int ni = 0; ni < 4; ++ni)
          acc[mi][ni] = MFMA16(af[mi], bfr[ni], acc[mi][ni]);
    }
    __syncthreads();
  }
  int m0 = bm * 128 + wr * 64;
  int n0 = bn * 128 + wc * 64;
#pragma unroll
  for (int ni = 0; ni < 4; ++ni) {
    int col = n0 + ni * 16 + (lane & 15);
    float bv = bias[col];
#pragma unroll
    for (int mi = 0; mi < 4; ++mi)
#pragma unroll
      for (int j = 0; j < 4; ++j) {
        int row = m0 + mi * 16 + (lane >> 4) * 4 + j;
        out[(size_t)row * 1024 + col] = acc[mi][ni][j] + bv;
      }
  }
}

// ---------- flash attention: causal, QBLK=64 (4 waves x 16 rows), KVBLK=64 ----------
__global__ __launch_bounds__(256) void attn_fwd(const u16* __restrict__ q,
                                                const u16* __restrict__ kk,
                                                const u16* __restrict__ vt,
                                                u16* __restrict__ att) {
  __shared__ u16 lK[64 * 64];
  __shared__ u16 lV[64 * 64];      // V^T tile: row = d, col = t
  __shared__ u16 lP[4][16 * 64];   // per-wave P scratch
  int tid = threadIdx.x, lane = tid & 63, w = tid >> 6;
  int bh = blockIdx.x, qt = blockIdx.y;
  const u16* qb = q + (size_t)bh * 2048 * 64;
  const u16* kb = kk + (size_t)bh * 2048 * 64;
  const u16* vb = vt + (size_t)bh * 64 * 2048;
  int q0 = qt * 64;
  int qrow = q0 + w * 16 + (lane & 15);
  bf16x8 aq[2];
#pragma unroll
  for (int s = 0; s < 2; ++s)
    aq[s] = *reinterpret_cast<const bf16x8*>(qb + (size_t)qrow * 64 + (lane >> 4) * 8 + s * 32);

  float m_r[4], l_r[4];
  f32x4 o[4] = {};
#pragma unroll
  for (int j = 0; j < 4; ++j) { m_r[j] = -1e30f; l_r[j] = 0.f; }

  for (int kt = 0; kt <= qt; ++kt) {
    // stage K tile [64 t][64 d] and V^T tile [64 d][64 t], swizzled source
#pragma unroll
    for (int i = 0; i < 2; ++i) {
      int r = w * 16 + i * 8 + (lane >> 3);
      int cs = (lane & 7) ^ (r & 7);
      gload_lds16(kb + (size_t)(kt * 64 + r) * 64 + cs * 8, lK + r * 64 + (lane & 7) * 8);
      gload_lds16(vb + (size_t)r * 2048 + kt * 64 + cs * 8, lV + r * 64 + (lane & 7) * 8);
    }
    __syncthreads();

    // S = (Q K^T) * scale
    f32x4 sf[4];
#pragma unroll
    for (int kc = 0; kc < 4; ++kc) {
      f32x4 sa = {};
      sa = MFMA16(aq[0], frag_read(lK, kc * 16 + (lane & 15), (lane >> 4)), sa);
      sa = MFMA16(aq[1], frag_read(lK, kc * 16 + (lane & 15), (lane >> 4) + 4), sa);
      sf[kc] = sa * 0.125f;
    }
    if (kt == qt) {
#pragma unroll
      for (int kc = 0; kc < 4; ++kc) {
        int kcol = kt * 64 + kc * 16 + (lane & 15);
#pragma unroll
        for (int j = 0; j < 4; ++j) {
          int qr = q0 + w * 16 + (lane >> 4) * 4 + j;
          if (kcol > qr) sf[kc][j] = -1e30f;
        }
      }
    }
    // row max across 16 lanes (cols) per fragment row
    float mx[4];
#pragma unroll
    for (int j = 0; j < 4; ++j)
      mx[j] = fmaxf(fmaxf(sf[0][j], sf[1][j]), fmaxf(sf[2][j], sf[3][j]));
#pragma unroll
    for (int dlt = 1; dlt < 16; dlt <<= 1)
#pragma unroll
      for (int j = 0; j < 4; ++j) mx[j] = fmaxf(mx[j], __shfl_xor(mx[j], dlt, 64));

    float sc[4], rs[4];
#pragma unroll
    for (int j = 0; j < 4; ++j) {
      float mn = fmaxf(m_r[j], mx[j]);
      sc[j] = __expf(m_r[j] - mn);
      m_r[j] = mn;
      rs[j] = 0.f;
    }
#pragma unroll
    for (int kc = 0; kc < 4; ++kc)
#pragma unroll
      for (int j = 0; j < 4; ++j) {
        float p = __expf(sf[kc][j] - m_r[j]);
        sf[kc][j] = p;
        rs[j] += p;
      }
#pragma unroll
    for (int dlt = 1; dlt < 16; dlt <<= 1)
#pragma unroll
      for (int j = 0; j < 4; ++j) rs[j] += __shfl_xor(rs[j], dlt, 64);
#pragma unroll
    for (int j = 0; j < 4; ++j) l_r[j] = l_r[j] * sc[j] + rs[j];
#pragma unroll
    for (int dc = 0; dc < 4; ++dc)
#pragma unroll
      for (int j = 0; j < 4; ++j) o[dc][j] *= sc[j];

    // write P (bf16) to per-wave swizzled LDS, then read as MFMA-A fragments
#pragma unroll
    for (int kc = 0; kc < 4; ++kc)
#pragma unroll
      for (int j = 0; j < 4; ++j) {
        int prow = (lane >> 4) * 4 + j;
        int colb = (kc * 16 + (lane & 15)) * 2;
        *reinterpret_cast<u16*>(reinterpret_cast<char*>(&lP[w][0]) + prow * 128 +
                                (colb ^ ((prow & 7) << 4))) = f2b(sf[kc][j]);
      }
    asm volatile("s_waitcnt lgkmcnt(0)" ::: "memory");
    __builtin_amdgcn_sched_barrier(0);
    __builtin_amdgcn_wave_barrier();

    bf16x8 ap0 = frag_read(&lP[w][0], lane & 15, (lane >> 4));
    bf16x8 ap1 = frag_read(&lP[w][0], lane & 15, (lane >> 4) + 4);
#pragma unroll
    for (int dc = 0; dc < 4; ++dc) {
      o[dc] = MFMA16(ap0, frag_read(lV, dc * 16 + (lane & 15), (lane >> 4)), o[dc]);
      o[dc] = MFMA16(ap1, frag_read(lV, dc * 16 + (lane & 15), (lane >> 4) + 4), o[dc]);
    }
    __syncthreads();
  }

  // epilogue: att[b][t][h*64+d] = O / l
  int b = bh >> 4, h = bh & 15;
#pragma unroll
  for (int dc = 0; dc < 4; ++dc)
#pragma unroll
    for (int j = 0; j < 4; ++j) {
      int t = q0 + w * 16 + (lane >> 4) * 4 + j;
      float val = o[dc][j] / l_r[j];
      att[(size_t)(b * 2048 + t) * 1024 + h * 64 + dc * 16 + (lane & 15)] = f2b(val);
    }
}

extern "C" void kernel_launch(void* const* d_in, const int* in_sizes, int n_in,
                              void* d_out, int out_size, void* d_ws, size_t ws_size,
                              hipStream_t stream) {
  const float* x = (const float*)d_in[0];
  const float* w_attn = (const float*)d_in[1];
  const float* b_attn = (const float*)d_in[2];
  const float* w_proj = (const float*)d_in[3];
  const float* b_proj = (const float*)d_in[4];
  float* out = (float*)d_out;

  // workspace (u16 units): xb 8.39M (aliased by att after gemm_qkv),
  // waT 3.15M, wpT 1.05M, vt 8.39M  => ~42 MB total
  u16* ws = (u16*)d_ws;
  u16* xb = ws;
  u16* waT = xb + 8388608;
  u16* wpT = waT + 3145728;
  u16* vtx = wpT + 1048576;
  u16* att = xb;  // alias: xb dead after gemm_qkv
  // q/k live in d_out (33.5MB) as scratch; overwritten by gemm_proj at the end
  u16* qx = (u16*)d_out;
  u16* kx = qx + 8388608;

  cvt_f32_bf16<<<8192, 256, 0, stream>>>(x, xb, 2097152);
  transpose_cvt<<<dim3(96, 32), 256, 0, stream>>>(w_attn, waT, 1024, 3072);
  transpose_cvt<<<dim3(32, 32), 256, 0, stream>>>(w_proj, wpT, 1024, 1024);
  gemm_qkv<<<dim3(64, 24), 256, 0, stream>>>(xb, waT, b_attn, qx, kx, vtx);
  attn_fwd<<<dim3(64, 32), 256, 0, stream>>>(qx, kx, vtx, att);
  gemm_proj<<<dim3(64, 8), 256, 0, stream>>>(att, wpT, b_proj, out);
}

// Round 2
// 239.085 us; speedup vs baseline: 1.1210x; 1.1210x over previous
//
#include <hip/hip_runtime.h>
#include <hip/hip_bf16.h>

typedef unsigned short u16;
typedef __bf16 bf16_t;
typedef bf16_t bf16x8 __attribute__((ext_vector_type(8)));
typedef float f32x4 __attribute__((ext_vector_type(4)));

#define MFMA16(a, b, c) __builtin_amdgcn_mfma_f32_16x16x32_bf16((a), (b), (c), 0, 0, 0)

__device__ __forceinline__ u16 f2b(float f) {
  bf16_t h = (bf16_t)f;
  return __builtin_bit_cast(u16, h);
}

__device__ __forceinline__ void gload_lds16(const void* src, void* dst) {
  __builtin_amdgcn_global_load_lds(
      (const __attribute__((address_space(1))) void*)src,
      (__attribute__((address_space(3))) void*)dst, 16, 0, 0);
}

// Read one 16B MFMA fragment from a swizzled LDS tile with 64-bf16 (128B) rows.
// Swizzle: 16B chunk c of row r is stored at chunk c ^ (r & 7).
__device__ __forceinline__ bf16x8 frag_read(const u16* tile, int row, int kchunk) {
  int off = row * 128 + ((kchunk ^ (row & 7)) << 4);
  return *reinterpret_cast<const bf16x8*>(reinterpret_cast<const char*>(tile) + off);
}

// Stage a 128-row x 64-bf16 tile (16KB) global->LDS, pre-swizzled global source
// so LDS dest stays linear (base + lane*16). 4 waves x 4 instrs, 8 rows each.
__device__ __forceinline__ void stage128(const u16* g, int rowStrideElts, u16* tile, int tid) {
  int lane = tid & 63, w = tid >> 6;
#pragma unroll
  for (int i = 0; i < 4; ++i) {
    int r = w * 32 + i * 8 + (lane >> 3);
    int cs = (lane & 7) ^ (r & 7);
    gload_lds16(g + (size_t)r * rowStrideElts + cs * 8, tile + r * 64 + (lane & 7) * 8);
  }
}

// ---------- convert / transpose ----------
__global__ __launch_bounds__(256) void cvt_f32_bf16(const float* __restrict__ in,
                                                    u16* __restrict__ out, int n4) {
  int i = blockIdx.x * 256 + threadIdx.x;
  if (i < n4) {
    float4 f = reinterpret_cast<const float4*>(in)[i];
    ushort4 o;
    o.x = f2b(f.x); o.y = f2b(f.y); o.z = f2b(f.z); o.w = f2b(f.w);
    reinterpret_cast<ushort4*>(out)[i] = o;
  }
}

// in[K][N] f32 -> out[N][K] bf16
__global__ __launch_bounds__(256) void transpose_cvt(const float* __restrict__ in,
                                                     u16* __restrict__ out, int K, int N) {
  __shared__ float t[32][33];
  int n0 = blockIdx.x * 32, k0 = blockIdx.y * 32;
  int tx = threadIdx.x & 31, ty = threadIdx.x >> 5;  // ty in 0..7
#pragma unroll
  for (int i = 0; i < 32; i += 8)
    t[ty + i][tx] = in[(size_t)(k0 + ty + i) * N + n0 + tx];
  __syncthreads();
#pragma unroll
  for (int i = 0; i < 32; i += 8)
    out[(size_t)(n0 + ty + i) * K + k0 + tx] = f2b(t[tx][ty + i]);
}

// ---------- GEMM1: qkv = x @ w_attn + b_attn, routed to q/k/vt ----------
__global__ __launch_bounds__(256) void gemm_qkv(const u16* __restrict__ xb,
                                                const u16* __restrict__ waT,
                                                const float* __restrict__ bias,
                                                u16* __restrict__ q, u16* __restrict__ kk,
                                                u16* __restrict__ vt) {
  __shared__ u16 lA[128 * 64];
  __shared__ u16 lB[128 * 64];
  int tid = threadIdx.x, lane = tid & 63, w = tid >> 6;
  int wr = w >> 1, wc = w & 1;
  int bm = blockIdx.x, bn = blockIdx.y;
  f32x4 acc[4][4] = {};
  const u16* gA = xb + (size_t)bm * 128 * 1024;
  const u16* gB = waT + (size_t)bn * 128 * 1024;
  for (int k0 = 0; k0 < 1024; k0 += 64) {
    stage128(gA + k0, 1024, lA, tid);
    stage128(gB + k0, 1024, lB, tid);
    __syncthreads();
#pragma unroll
    for (int s = 0; s < 2; ++s) {
      bf16x8 af[4], bfr[4];
#pragma unroll
      for (int mi = 0; mi < 4; ++mi)
        af[mi] = frag_read(lA, wr * 64 + mi * 16 + (lane & 15), (lane >> 4) + s * 4);
#pragma unroll
      for (int ni = 0; ni < 4; ++ni)
        bfr[ni] = frag_read(lB, wc * 64 + ni * 16 + (lane & 15), (lane >> 4) + s * 4);
#pragma unroll
      for (int mi = 0; mi < 4; ++mi)
#pragma unroll
        for (int ni = 0; ni < 4; ++ni)
          acc[mi][ni] = MFMA16(af[mi], bfr[ni], acc[mi][ni]);
    }
    __syncthreads();
  }
  int m0 = bm * 128 + wr * 64;
  int n0 = bn * 128 + wc * 64;
#pragma unroll
  for (int ni = 0; ni < 4; ++ni) {
    int col = n0 + ni * 16 + (lane & 15);
    float bv = bias[col];
    int part = col >> 10;
    int cin = col & 1023;
    int h = cin >> 6, d = cin & 63;
#pragma unroll
    for (int mi = 0; mi < 4; ++mi) {
#pragma unroll
      for (int j = 0; j < 4; ++j) {
        int row = m0 + mi * 16 + (lane >> 4) * 4 + j;
        int b = row >> 11, t = row & 2047;
        u16 hv = f2b(acc[mi][ni][j] + bv);
        if (part == 0)
          q[(((size_t)(b * 16 + h) * 2048 + t) << 6) + d] = hv;
        else if (part == 1)
          kk[(((size_t)(b * 16 + h) * 2048 + t) << 6) + d] = hv;
        else
          vt[(((size_t)(b * 16 + h) << 6) + d) * 2048 + t] = hv;  // V pre-transposed [D][T]
      }
    }
  }
}

// ---------- GEMM2: out = att @ w_proj + b_proj (f32 out) ----------
__global__ __launch_bounds__(256) void gemm_proj(const u16* __restrict__ att,
                                                 const u16* __restrict__ wpT,
                                                 const float* __restrict__ bias,
                                                 float* __restrict__ out) {
  __shared__ u16 lA[128 * 64];
  __shared__ u16 lB[128 * 64];
  int tid = threadIdx.x, lane = tid & 63, w = tid >> 6;
  int wr = w >> 1, wc = w & 1;
  int bm = blockIdx.x, bn = blockIdx.y;
  f32x4 acc[4][4] = {};
  const u16* gA = att + (size_t)bm * 128 * 1024;
  const u16* gB = wpT + (size_t)bn * 128 * 1024;
  for (int k0 = 0; k0 < 1024; k0 += 64) {
    stage128(gA + k0, 1024, lA, tid);
    stage128(gB + k0, 1024, lB, tid);
    __syncthreads();
#pragma unroll
    for (int s = 0; s < 2; ++s) {
      bf16x8 af[4], bfr[4];
#pragma unroll
      for (int mi = 0; mi < 4; ++mi)
        af[mi] = frag_read(lA, wr * 64 + mi * 16 + (lane & 15), (lane >> 4) + s * 4);
#pragma unroll
      for (int ni = 0; ni < 4; ++ni)
        bfr[ni] = frag_read(lB, wc * 64 + ni * 16 + (lane & 15), (lane >> 4) + s * 4);
#pragma unroll
      for (int mi = 0; mi < 4; ++mi)
#pragma unroll
        for (int ni = 0; ni < 4; ++ni)
          acc[mi][ni] = MFMA16(af[mi], bfr[ni], acc[mi][ni]);
    }
    __syncthreads();
  }
  int m0 = bm * 128 + wr * 64;
  int n0 = bn * 128 + wc * 64;
#pragma unroll
  for (int ni = 0; ni < 4; ++ni) {
    int col = n0 + ni * 16 + (lane & 15);
    float bv = bias[col];
#pragma unroll
    for (int mi = 0; mi < 4; ++mi)
#pragma unroll
      for (int j = 0; j < 4; ++j) {
        int row = m0 + mi * 16 + (lane >> 4) * 4 + j;
        out[(size_t)row * 1024 + col] = acc[mi][ni][j] + bv;
      }
  }
}

// ---------- flash attention ----------
// Causal pairing: block (bh, y) handles q-tiles qtA=y and qtB=31-y in one
// interleaved kt loop (every block = 33 compute-tiles, perfectly balanced).
// K/V tiles double-buffered: STAGE(kt+1) issued before compute(kt); one
// barrier per tile; vmcnt drains at the barrier after a full compute phase.

// stage K tile [64 t][64 d] and V^T tile [64 d][64 t], swizzled source
__device__ __forceinline__ void stage_kv(const u16* kb, const u16* vb, int kt,
                                         u16* lK, u16* lV, int tid) {
  int lane = tid & 63, w = tid >> 6;
#pragma unroll
  for (int i = 0; i < 2; ++i) {
    int r = w * 16 + i * 8 + (lane >> 3);
    int cs = (lane & 7) ^ (r & 7);
    gload_lds16(kb + (size_t)(kt * 64 + r) * 64 + cs * 8, lK + r * 64 + (lane & 7) * 8);
    gload_lds16(vb + (size_t)r * 2048 + kt * 64 + cs * 8, lV + r * 64 + (lane & 7) * 8);
  }
}

// one (Q-tile x KV-tile) step for a 16-row wave fragment
__device__ __forceinline__ void attn_tile(const bf16x8 aq0, const bf16x8 aq1,
                                          float* m_r, float* l_r, f32x4* o,
                                          const u16* lK, const u16* lV, u16* lPw,
                                          int lane, int qrow0, int k0, bool domask) {
  f32x4 sf[4];
  __builtin_amdgcn_s_setprio(1);
#pragma unroll
  for (int kc = 0; kc < 4; ++kc) {
    f32x4 sa = {};
    sa = MFMA16(aq0, frag_read(lK, kc * 16 + (lane & 15), (lane >> 4)), sa);
    sa = MFMA16(aq1, frag_read(lK, kc * 16 + (lane & 15), (lane >> 4) + 4), sa);
    sf[kc] = sa * 0.125f;
  }
  __builtin_amdgcn_s_setprio(0);
  if (domask) {
#pragma unroll
    for (int kc = 0; kc < 4; ++kc) {
      int kcol = k0 + kc * 16 + (lane & 15);
#pragma unroll
      for (int j = 0; j < 4; ++j) {
        int qr = qrow0 + (lane >> 4) * 4 + j;
        if (kcol > qr) sf[kc][j] = -1e30f;
      }
    }
  }
  // row max across the 16 lanes holding this row's columns
  float mx[4];
#pragma unroll
  for (int j = 0; j < 4; ++j)
    mx[j] = fmaxf(fmaxf(sf[0][j], sf[1][j]), fmaxf(sf[2][j], sf[3][j]));
#pragma unroll
  for (int dlt = 1; dlt < 16; dlt <<= 1)
#pragma unroll
    for (int j = 0; j < 4; ++j) mx[j] = fmaxf(mx[j], __shfl_xor(mx[j], dlt, 64));

  float sc[4], rs[4];
#pragma unroll
  for (int j = 0; j < 4; ++j) {
    float mn = fmaxf(m_r[j], mx[j]);
    sc[j] = __expf(m_r[j] - mn);
    m_r[j] = mn;
    rs[j] = 0.f;
  }
#pragma unroll
  for (int kc = 0; kc < 4; ++kc)
#pragma unroll
    for (int j = 0; j < 4; ++j) {
      float p = __expf(sf[kc][j] - m_r[j]);
      sf[kc][j] = p;
      rs[j] += p;
    }
#pragma unroll
  for (int dlt = 1; dlt < 16; dlt <<= 1)
#pragma unroll
    for (int j = 0; j < 4; ++j) rs[j] += __shfl_xor(rs[j], dlt, 64);
#pragma unroll
  for (int j = 0; j < 4; ++j) l_r[j] = l_r[j] * sc[j] + rs[j];
#pragma unroll
  for (int dc = 0; dc < 4; ++dc)
#pragma unroll
    for (int j = 0; j < 4; ++j) o[dc][j] *= sc[j];

  // write P (bf16) to per-wave swizzled LDS, then read as MFMA-A fragments
#pragma unroll
  for (int kc = 0; kc < 4; ++kc)
#pragma unroll
    for (int j = 0; j < 4; ++j) {
      int prow = (lane >> 4) * 4 + j;
      int colb = (kc * 16 + (lane & 15)) * 2;
      *reinterpret_cast<u16*>(reinterpret_cast<char*>(lPw) + prow * 128 +
                              (colb ^ ((prow & 7) << 4))) = f2b(sf[kc][j]);
    }
  asm volatile("s_waitcnt lgkmcnt(0)" ::: "memory");
  __builtin_amdgcn_sched_barrier(0);
  __builtin_amdgcn_wave_barrier();

  bf16x8 ap0 = frag_read(lPw, lane & 15, (lane >> 4));
  bf16x8 ap1 = frag_read(lPw, lane & 15, (lane >> 4) + 4);
  __builtin_amdgcn_s_setprio(1);
#pragma unroll
  for (int dc = 0; dc < 4; ++dc) {
    o[dc] = MFMA16(ap0, frag_read(lV, dc * 16 + (lane & 15), (lane >> 4)), o[dc]);
    o[dc] = MFMA16(ap1, frag_read(lV, dc * 16 + (lane & 15), (lane >> 4) + 4), o[dc]);
  }
  __builtin_amdgcn_s_setprio(0);
  __builtin_amdgcn_sched_barrier(0);  // pin: next caller's lP writes must not hoist above these reads
}

__device__ __forceinline__ void attn_epi(const float* l_r, const f32x4* o,
                                         u16* __restrict__ att, int b, int h,
                                         int qrow0, int lane) {
#pragma unroll
  for (int j = 0; j < 4; ++j) {
    float inv = __builtin_amdgcn_rcpf(l_r[j]);
    int t = qrow0 + (lane >> 4) * 4 + j;
#pragma unroll
    for (int dc = 0; dc < 4; ++dc)
      att[(size_t)(b * 2048 + t) * 1024 + h * 64 + dc * 16 + (lane & 15)] =
          f2b(o[dc][j] * inv);
  }
}

__global__ __launch_bounds__(256, 3) void attn_fwd(const u16* __restrict__ q,
                                                   const u16* __restrict__ kk,
                                                   const u16* __restrict__ vt,
                                                   u16* __restrict__ att) {
  __shared__ u16 lK[2][64 * 64];
  __shared__ u16 lV[2][64 * 64];
  __shared__ u16 lP[4][16 * 64];
  int tid = threadIdx.x, lane = tid & 63, w = tid >> 6;
  int bh = blockIdx.x;
  int qtA = blockIdx.y;       // 0..15
  int qtB = 31 - qtA;         // 16..31
  const u16* qb = q + (size_t)bh * 2048 * 64;
  const u16* kb = kk + (size_t)bh * 2048 * 64;
  const u16* vb = vt + (size_t)bh * 64 * 2048;
  int q0A = qtA * 64 + w * 16;
  int q0B = qtB * 64 + w * 16;

  bf16x8 aqA0, aqA1, aqB0, aqB1;
  {
    int qrA = q0A + (lane & 15);
    int qrB = q0B + (lane & 15);
    const u16* pa = qb + (size_t)qrA * 64 + (lane >> 4) * 8;
    const u16* pb = qb + (size_t)qrB * 64 + (lane >> 4) * 8;
    aqA0 = *reinterpret_cast<const bf16x8*>(pa);
    aqA1 = *reinterpret_cast<const bf16x8*>(pa + 32);
    aqB0 = *reinterpret_cast<const bf16x8*>(pb);
    aqB1 = *reinterpret_cast<const bf16x8*>(pb + 32);
  }

  float mA[4], lAr[4], mB[4], lBr[4];
  f32x4 oA[4] = {}, oB[4] = {};
#pragma unroll
  for (int j = 0; j < 4; ++j) { mA[j] = -1e30f; lAr[j] = 0.f; mB[j] = -1e30f; lBr[j] = 0.f; }

  stage_kv(kb, vb, 0, &lK[0][0], &lV[0][0], tid);

  for (int kt = 0; kt <= qtB; ++kt) {
    int cur = kt & 1;
    __syncthreads();  // tile kt landed (vmcnt drains here); prev compute done
    if (kt < qtB) stage_kv(kb, vb, kt + 1, &lK[cur ^ 1][0], &lV[cur ^ 1][0], tid);
    attn_tile(aqB0, aqB1, mB, lBr, oB, &lK[cur][0], &lV[cur][0], &lP[w][0],
              lane, q0B, kt * 64, kt == qtB);
    if (kt <= qtA)
      attn_tile(aqA0, aqA1, mA, lAr, oA, &lK[cur][0], &lV[cur][0], &lP[w][0],
                lane, q0A, kt * 64, kt == qtA);
  }

  int b = bh >> 4, h = bh & 15;
  attn_epi(lBr, oB, att, b, h, q0B, lane);
  attn_epi(lAr, oA, att, b, h, q0A, lane);
}

extern "C" void kernel_launch(void* const* d_in, const int* in_sizes, int n_in,
                              void* d_out, int out_size, void* d_ws, size_t ws_size,
                              hipStream_t stream) {
  const float* x = (const float*)d_in[0];
  const float* w_attn = (const float*)d_in[1];
  const float* b_attn = (const float*)d_in[2];
  const float* w_proj = (const float*)d_in[3];
  const float* b_proj = (const float*)d_in[4];
  float* out = (float*)d_out;

  // workspace (u16 units): xb 8.39M (aliased by att after gemm_qkv),
  // waT 3.15M, wpT 1.05M, vt 8.39M  => ~42 MB total
  u16* ws = (u16*)d_ws;
  u16* xb = ws;
  u16* waT = xb + 8388608;
  u16* wpT = waT + 3145728;
  u16* vtx = wpT + 1048576;
  u16* att = xb;  // alias: xb dead after gemm_qkv
  // q/k live in d_out (33.5MB) as scratch; overwritten by gemm_proj at the end
  u16* qx = (u16*)d_out;
  u16* kx = qx + 8388608;

  cvt_f32_bf16<<<8192, 256, 0, stream>>>(x, xb, 2097152);
  transpose_cvt<<<dim3(96, 32), 256, 0, stream>>>(w_attn, waT, 1024, 3072);
  transpose_cvt<<<dim3(32, 32), 256, 0, stream>>>(w_proj, wpT, 1024, 1024);
  gemm_qkv<<<dim3(64, 24), 256, 0, stream>>>(xb, waT, b_attn, qx, kx, vtx);
  attn_fwd<<<dim3(64, 16), 256, 0, stream>>>(qx, kx, vtx, att);
  gemm_proj<<<dim3(64, 8), 256, 0, stream>>>(att, wpT, b_proj, out);
}

// Round 3
// 221.827 us; speedup vs baseline: 1.2082x; 1.0778x over previous
//
#include <hip/hip_runtime.h>
#include <hip/hip_bf16.h>

typedef unsigned short u16;
typedef __bf16 bf16_t;
typedef bf16_t bf16x8 __attribute__((ext_vector_type(8)));
typedef float f32x4 __attribute__((ext_vector_type(4)));
typedef u16 u16x4 __attribute__((ext_vector_type(4)));

#define MFMA16(a, b, c) __builtin_amdgcn_mfma_f32_16x16x32_bf16((a), (b), (c), 0, 0, 0)

__device__ __forceinline__ u16 f2b(float f) {
  bf16_t h = (bf16_t)f;
  return __builtin_bit_cast(u16, h);
}

__device__ __forceinline__ void gload_lds16(const void* src, void* dst) {
  __builtin_amdgcn_global_load_lds(
      (const __attribute__((address_space(1))) void*)src,
      (__attribute__((address_space(3))) void*)dst, 16, 0, 0);
}

// Read one 16B MFMA fragment from a swizzled LDS tile with 64-bf16 (128B) rows.
// Swizzle: 16B chunk c of row r is stored at chunk c ^ (r & 7).
__device__ __forceinline__ bf16x8 frag_read(const u16* tile, int row, int kchunk) {
  int off = row * 128 + ((kchunk ^ (row & 7)) << 4);
  return *reinterpret_cast<const bf16x8*>(reinterpret_cast<const char*>(tile) + off);
}

// Stage a 128-row x 64-bf16 tile (16KB) global->LDS, pre-swizzled global source
// so LDS dest stays linear (base + lane*16). 4 waves x 4 instrs, 8 rows each.
__device__ __forceinline__ void stage128(const u16* g, int rowStrideElts, u16* tile, int tid) {
  int lane = tid & 63, w = tid >> 6;
#pragma unroll
  for (int i = 0; i < 4; ++i) {
    int r = w * 32 + i * 8 + (lane >> 3);
    int cs = (lane & 7) ^ (r & 7);
    gload_lds16(g + (size_t)r * rowStrideElts + cs * 8, tile + r * 64 + (lane & 7) * 8);
  }
}

// ---------- convert / transpose ----------
__global__ __launch_bounds__(256) void cvt_f32_bf16(const float* __restrict__ in,
                                                    u16* __restrict__ out, int n4) {
  int i = blockIdx.x * 256 + threadIdx.x;
  if (i < n4) {
    float4 f = reinterpret_cast<const float4*>(in)[i];
    ushort4 o;
    o.x = f2b(f.x); o.y = f2b(f.y); o.z = f2b(f.z); o.w = f2b(f.w);
    reinterpret_cast<ushort4*>(out)[i] = o;
  }
}

// in[K][N] f32 -> out[N][K] bf16
__global__ __launch_bounds__(256) void transpose_cvt(const float* __restrict__ in,
                                                     u16* __restrict__ out, int K, int N) {
  __shared__ float t[32][33];
  int n0 = blockIdx.x * 32, k0 = blockIdx.y * 32;
  int tx = threadIdx.x & 31, ty = threadIdx.x >> 5;  // ty in 0..7
#pragma unroll
  for (int i = 0; i < 32; i += 8)
    t[ty + i][tx] = in[(size_t)(k0 + ty + i) * N + n0 + tx];
  __syncthreads();
#pragma unroll
  for (int i = 0; i < 32; i += 8)
    out[(size_t)(n0 + ty + i) * K + k0 + tx] = f2b(t[tx][ty + i]);
}

// ---------- GEMM1: qkv = x @ w_attn + b_attn, routed to q/k/vt ----------
__global__ __launch_bounds__(256) void gemm_qkv(const u16* __restrict__ xb,
                                                const u16* __restrict__ waT,
                                                const float* __restrict__ bias,
                                                u16* __restrict__ q, u16* __restrict__ kk,
                                                u16* __restrict__ vt) {
  __shared__ u16 lA[128 * 64];
  __shared__ u16 lB[128 * 64];
  int tid = threadIdx.x, lane = tid & 63, w = tid >> 6;
  int wr = w >> 1, wc = w & 1;
  int bm = blockIdx.x, bn = blockIdx.y;
  f32x4 acc[4][4] = {};
  const u16* gA = xb + (size_t)bm * 128 * 1024;
  const u16* gB = waT + (size_t)bn * 128 * 1024;
  for (int k0 = 0; k0 < 1024; k0 += 64) {
    stage128(gA + k0, 1024, lA, tid);
    stage128(gB + k0, 1024, lB, tid);
    __syncthreads();
#pragma unroll
    for (int s = 0; s < 2; ++s) {
      bf16x8 af[4], bfr[4];
#pragma unroll
      for (int mi = 0; mi < 4; ++mi)
        af[mi] = frag_read(lA, wr * 64 + mi * 16 + (lane & 15), (lane >> 4) + s * 4);
#pragma unroll
      for (int ni = 0; ni < 4; ++ni)
        bfr[ni] = frag_read(lB, wc * 64 + ni * 16 + (lane & 15), (lane >> 4) + s * 4);
#pragma unroll
      for (int mi = 0; mi < 4; ++mi)
#pragma unroll
        for (int ni = 0; ni < 4; ++ni)
          acc[mi][ni] = MFMA16(af[mi], bfr[ni], acc[mi][ni]);
    }
    __syncthreads();
  }
  int m0 = bm * 128 + wr * 64;
  int n0 = bn * 128 + wc * 64;
#pragma unroll
  for (int ni = 0; ni < 4; ++ni) {
    int col = n0 + ni * 16 + (lane & 15);
    float bv = bias[col];
    int part = col >> 10;
    int cin = col & 1023;
    int h = cin >> 6, d = cin & 63;
#pragma unroll
    for (int mi = 0; mi < 4; ++mi) {
#pragma unroll
      for (int j = 0; j < 4; ++j) {
        int row = m0 + mi * 16 + (lane >> 4) * 4 + j;
        int b = row >> 11, t = row & 2047;
        u16 hv = f2b(acc[mi][ni][j] + bv);
        if (part == 0)
          q[(((size_t)(b * 16 + h) * 2048 + t) << 6) + d] = hv;
        else if (part == 1)
          kk[(((size_t)(b * 16 + h) * 2048 + t) << 6) + d] = hv;
        else
          vt[(((size_t)(b * 16 + h) << 6) + d) * 2048 + t] = hv;  // V pre-transposed [D][T]
      }
    }
  }
}

// ---------- GEMM2: out = att @ w_proj + b_proj (f32 out) ----------
__global__ __launch_bounds__(256) void gemm_proj(const u16* __restrict__ att,
                                                 const u16* __restrict__ wpT,
                                                 const float* __restrict__ bias,
                                                 float* __restrict__ out) {
  __shared__ u16 lA[128 * 64];
  __shared__ u16 lB[128 * 64];
  int tid = threadIdx.x, lane = tid & 63, w = tid >> 6;
  int wr = w >> 1, wc = w & 1;
  int bm = blockIdx.x, bn = blockIdx.y;
  f32x4 acc[4][4] = {};
  const u16* gA = att + (size_t)bm * 128 * 1024;
  const u16* gB = wpT + (size_t)bn * 128 * 1024;
  for (int k0 = 0; k0 < 1024; k0 += 64) {
    stage128(gA + k0, 1024, lA, tid);
    stage128(gB + k0, 1024, lB, tid);
    __syncthreads();
#pragma unroll
    for (int s = 0; s < 2; ++s) {
      bf16x8 af[4], bfr[4];
#pragma unroll
      for (int mi = 0; mi < 4; ++mi)
        af[mi] = frag_read(lA, wr * 64 + mi * 16 + (lane & 15), (lane >> 4) + s * 4);
#pragma unroll
      for (int ni = 0; ni < 4; ++ni)
        bfr[ni] = frag_read(lB, wc * 64 + ni * 16 + (lane & 15), (lane >> 4) + s * 4);
#pragma unroll
      for (int mi = 0; mi < 4; ++mi)
#pragma unroll
        for (int ni = 0; ni < 4; ++ni)
          acc[mi][ni] = MFMA16(af[mi], bfr[ni], acc[mi][ni]);
    }
    __syncthreads();
  }
  int m0 = bm * 128 + wr * 64;
  int n0 = bn * 128 + wc * 64;
#pragma unroll
  for (int ni = 0; ni < 4; ++ni) {
    int col = n0 + ni * 16 + (lane & 15);
    float bv = bias[col];
#pragma unroll
    for (int mi = 0; mi < 4; ++mi)
#pragma unroll
      for (int j = 0; j < 4; ++j) {
        int row = m0 + mi * 16 + (lane >> 4) * 4 + j;
        out[(size_t)row * 1024 + col] = acc[mi][ni][j] + bv;
      }
  }
}

// ---------- flash attention, swapped-operand form ----------
// S^T = mfma(K_frag, Q_frag): each lane owns one q-column (q = lane&15) with
// 16 in-register k-values => in-lane row-max/sum + 2 shfl_xor; scalar m/l.
// O^T = mfma(V^T_frag, P^T_frag); epilogue transposes O^T via per-wave LDS.
// Causal pairing: block (bh,y) handles q-tiles y and 31-y (33 tiles each).

__device__ __forceinline__ void stage_kv(const u16* kb, const u16* vb, int kt,
                                         u16* lK, u16* lV, int tid) {
  int lane = tid & 63, w = tid >> 6;
#pragma unroll
  for (int i = 0; i < 2; ++i) {
    int r = w * 16 + i * 8 + (lane >> 3);
    int cs = (lane & 7) ^ (r & 7);
    gload_lds16(kb + (size_t)(kt * 64 + r) * 64 + cs * 8, lK + r * 64 + (lane & 7) * 8);
    gload_lds16(vb + (size_t)r * 2048 + kt * 64 + cs * 8, lV + r * 64 + (lane & 7) * 8);
  }
}

__global__ __launch_bounds__(256, 3) void attn_fwd(const u16* __restrict__ q,
                                                   const u16* __restrict__ kk,
                                                   const u16* __restrict__ vt,
                                                   u16* __restrict__ att) {
  __shared__ u16 lK[2][64 * 64];
  __shared__ u16 lV[2][64 * 64];
  __shared__ u16 lP[4][16 * 64];
  int tid = threadIdx.x, lane = tid & 63, w = tid >> 6;
  int ln = lane & 15, g = lane >> 4;
  int gh = g >> 1, gl = g & 1;
  int bh = blockIdx.x;
  int qtA = blockIdx.y;   // 0..15
  int qtB = 31 - qtA;     // 16..31
  const u16* qb = q + (size_t)bh * 2048 * 64;
  const u16* kb = kk + (size_t)bh * 2048 * 64;
  const u16* vb = vt + (size_t)bh * 64 * 2048;
  int q0A = qtA * 64 + w * 16;
  int q0B = qtB * 64 + w * 16;
  u16* lPw = &lP[w][0];
  int prow = ln * 128;            // byte base of this lane's P row
  int xorq = (ln & 7) << 4;       // swizzle XOR for this row

  bf16x8 aqA[2], aqB[2];
  {
    const u16* pa = qb + (size_t)(q0A + ln) * 64 + g * 8;
    const u16* pb = qb + (size_t)(q0B + ln) * 64 + g * 8;
    aqA[0] = *reinterpret_cast<const bf16x8*>(pa);
    aqA[1] = *reinterpret_cast<const bf16x8*>(pa + 32);
    aqB[0] = *reinterpret_cast<const bf16x8*>(pb);
    aqB[1] = *reinterpret_cast<const bf16x8*>(pb + 32);
  }

  float mA = -1e30f, lA = 0.f, mB = -1e30f, lB = 0.f;
  f32x4 oA[4] = {}, oB[4] = {};

  constexpr float SCL = 0.18033688011112042f;  // 0.125 * log2(e)

  // process one Q-state against the current K/V tile (everything in log2 domain)
  auto proc_state = [&](f32x4* sf, float& m_r, float& l_r, f32x4* o,
                        bool domask, int k0, int qg, const u16* Vt) {
#pragma unroll
    for (int kc = 0; kc < 4; ++kc) sf[kc] *= SCL;
    if (domask) {
#pragma unroll
      for (int kc = 0; kc < 4; ++kc)
#pragma unroll
        for (int j = 0; j < 4; ++j)
          if (k0 + kc * 16 + g * 4 + j > qg) sf[kc][j] = -1e30f;
    }
    // in-lane max over 16 values, then across the 4 lane-groups
    f32x4 m4;
#pragma unroll
    for (int j = 0; j < 4; ++j)
      m4[j] = fmaxf(fmaxf(sf[0][j], sf[1][j]), fmaxf(sf[2][j], sf[3][j]));
    float mx = fmaxf(fmaxf(m4[0], m4[1]), fmaxf(m4[2], m4[3]));
    mx = fmaxf(mx, __shfl_xor(mx, 16, 64));
    mx = fmaxf(mx, __shfl_xor(mx, 32, 64));
    if (!__all(mx - m_r <= 8.f)) {   // defer-max: rescale only on big growth
      float mn = fmaxf(m_r, mx);
      float sc = exp2f(m_r - mn);
      m_r = mn;
      l_r *= sc;
#pragma unroll
      for (int dc = 0; dc < 4; ++dc) o[dc] *= sc;
    }
    float rs = 0.f;
#pragma unroll
    for (int kc = 0; kc < 4; ++kc) {
      u16x4 v4;
#pragma unroll
      for (int j = 0; j < 4; ++j) {
        float p = exp2f(sf[kc][j] - m_r);
        rs += p;
        v4[j] = f2b(p);
      }
      // P[q][k]: k = 16*kc + 4*g + j  -> chunk 2*kc+gh (swizzled), 8B at gl*8
      *reinterpret_cast<u16x4*>(reinterpret_cast<char*>(lPw) + prow +
                                ((((kc << 1) + gh) << 4) ^ xorq) + gl * 8) = v4;
    }
    rs += __shfl_xor(rs, 16, 64);
    rs += __shfl_xor(rs, 32, 64);
    l_r += rs;
    asm volatile("s_waitcnt lgkmcnt(0)" ::: "memory");
    __builtin_amdgcn_sched_barrier(0);
    __builtin_amdgcn_wave_barrier();
    bf16x8 bp0 = frag_read(lPw, ln, g);
    bf16x8 bp1 = frag_read(lPw, ln, g + 4);
    __builtin_amdgcn_sched_barrier(0);   // pin: later lP writes stay after these reads
    __builtin_amdgcn_s_setprio(1);
#pragma unroll
    for (int dc = 0; dc < 4; ++dc) {
      o[dc] = MFMA16(frag_read(Vt, dc * 16 + ln, g), bp0, o[dc]);
      o[dc] = MFMA16(frag_read(Vt, dc * 16 + ln, g + 4), bp1, o[dc]);
    }
    __builtin_amdgcn_s_setprio(0);
  };

  stage_kv(kb, vb, 0, &lK[0][0], &lV[0][0], tid);

  for (int kt = 0; kt <= qtB; ++kt) {
    int cur = kt & 1;
    __syncthreads();  // tile kt landed; previous compute done
    if (kt < qtB) stage_kv(kb, vb, kt + 1, &lK[cur ^ 1][0], &lV[cur ^ 1][0], tid);
    const u16* Kt = &lK[cur][0];
    const u16* Vt = &lV[cur][0];
    bool doA = (kt <= qtA);

    // QK^T both states, K-fragments shared
    f32x4 sB[4], sA[4];
    __builtin_amdgcn_s_setprio(1);
#pragma unroll
    for (int kc = 0; kc < 4; ++kc) {
      f32x4 zB = {}, zA = {};
#pragma unroll
      for (int s = 0; s < 2; ++s) {
        bf16x8 kf = frag_read(Kt, kc * 16 + ln, g + 4 * s);
        zB = MFMA16(kf, aqB[s], zB);
        if (doA) zA = MFMA16(kf, aqA[s], zA);
      }
      sB[kc] = zB;
      sA[kc] = zA;
    }
    __builtin_amdgcn_s_setprio(0);

    proc_state(sB, mB, lB, oB, kt == qtB, kt * 64, q0B + ln, Vt);
    if (doA) proc_state(sA, mA, lA, oA, kt == qtA, kt * 64, q0A + ln, Vt);
  }

  // epilogue: transpose O^T -> O via per-wave lP tile, coalesced 16B stores
  int b = bh >> 4, h = bh & 15;
  auto epi = [&](const f32x4* o, float l_r, int q0w) {
    float inv = __builtin_amdgcn_rcpf(l_r);
#pragma unroll
    for (int dc = 0; dc < 4; ++dc) {
      u16x4 v4;
#pragma unroll
      for (int j = 0; j < 4; ++j) v4[j] = f2b(o[dc][j] * inv);
      // O^T row d = 16*dc + 4*g + j, col q=ln  -> store at lP[q][d]
      *reinterpret_cast<u16x4*>(reinterpret_cast<char*>(lPw) + prow +
                                ((((dc << 1) + gh) << 4) ^ xorq) + gl * 8) = v4;
    }
    asm volatile("s_waitcnt lgkmcnt(0)" ::: "memory");
    __builtin_amdgcn_sched_barrier(0);
    __builtin_amdgcn_wave_barrier();
    bf16x8 r0 = frag_read(lPw, ln, g);
    bf16x8 r1 = frag_read(lPw, ln, g + 4);
    __builtin_amdgcn_sched_barrier(0);
    int t = q0w + ln;
    u16* dst = att + (size_t)(b * 2048 + t) * 1024 + h * 64;
    *reinterpret_cast<bf16x8*>(dst + g * 8) = r0;
    *reinterpret_cast<bf16x8*>(dst + 32 + g * 8) = r1;
  };
  epi(oB, lB, q0B);
  epi(oA, lA, q0A);
}

extern "C" void kernel_launch(void* const* d_in, const int* in_sizes, int n_in,
                              void* d_out, int out_size, void* d_ws, size_t ws_size,
                              hipStream_t stream) {
  const float* x = (const float*)d_in[0];
  const float* w_attn = (const float*)d_in[1];
  const float* b_attn = (const float*)d_in[2];
  const float* w_proj = (const float*)d_in[3];
  const float* b_proj = (const float*)d_in[4];
  float* out = (float*)d_out;

  // workspace (u16 units): xb 8.39M (aliased by att after gemm_qkv),
  // waT 3.15M, wpT 1.05M, vt 8.39M  => ~42 MB total
  u16* ws = (u16*)d_ws;
  u16* xb = ws;
  u16* waT = xb + 8388608;
  u16* wpT = waT + 3145728;
  u16* vtx = wpT + 1048576;
  u16* att = xb;  // alias: xb dead after gemm_qkv
  // q/k live in d_out (33.5MB) as scratch; overwritten by gemm_proj at the end
  u16* qx = (u16*)d_out;
  u16* kx = qx + 8388608;

  cvt_f32_bf16<<<8192, 256, 0, stream>>>(x, xb, 2097152);
  transpose_cvt<<<dim3(96, 32), 256, 0, stream>>>(w_attn, waT, 1024, 3072);
  transpose_cvt<<<dim3(32, 32), 256, 0, stream>>>(w_proj, wpT, 1024, 1024);
  gemm_qkv<<<dim3(64, 24), 256, 0, stream>>>(xb, waT, b_attn, qx, kx, vtx);
  attn_fwd<<<dim3(64, 16), 256, 0, stream>>>(qx, kx, vtx, att);
  gemm_proj<<<dim3(64, 8), 256, 0, stream>>>(att, wpT, b_proj, out);
}

// Round 4
// 209.141 us; speedup vs baseline: 1.2815x; 1.0607x over previous
//
#include <hip/hip_runtime.h>
#include <hip/hip_bf16.h>

typedef unsigned short u16;
typedef unsigned int u32;
typedef __bf16 bf16_t;
typedef bf16_t bf16x8 __attribute__((ext_vector_type(8)));
typedef float f32x4 __attribute__((ext_vector_type(4)));
typedef u16 u16x4 __attribute__((ext_vector_type(4)));
typedef u32 u32x2 __attribute__((ext_vector_type(2)));
typedef u32 u32x4 __attribute__((ext_vector_type(4)));
typedef int intx2 __attribute__((ext_vector_type(2)));

#define MFMA16(a, b, c) __builtin_amdgcn_mfma_f32_16x16x32_bf16((a), (b), (c), 0, 0, 0)

// softmax scale folded into Q: 1/sqrt(64) * log2(e)
#define QSCL 0.18033688011112042f

__device__ __forceinline__ u16 f2b(float f) {
  bf16_t h = (bf16_t)f;
  return __builtin_bit_cast(u16, h);
}

__device__ __forceinline__ void gload_lds16(const void* src, void* dst) {
  __builtin_amdgcn_global_load_lds(
      (const __attribute__((address_space(1))) void*)src,
      (__attribute__((address_space(3))) void*)dst, 16, 0, 0);
}

// Read one 16B MFMA fragment from a swizzled LDS tile with 64-bf16 (128B) rows.
// Swizzle: 16B chunk c of row r is stored at chunk c ^ (r & 7).
__device__ __forceinline__ bf16x8 frag_read(const u16* tile, int row, int kchunk) {
  int off = row * 128 + ((kchunk ^ (row & 7)) << 4);
  return *reinterpret_cast<const bf16x8*>(reinterpret_cast<const char*>(tile) + off);
}

// Stage a 128-row x 64-bf16 tile (16KB) global->LDS, pre-swizzled global source
// so LDS dest stays linear (base + lane*16). 4 waves x 4 instrs, 8 rows each.
__device__ __forceinline__ void stage128(const u16* g, int rowStrideElts, u16* tile, int tid) {
  int lane = tid & 63, w = tid >> 6;
#pragma unroll
  for (int i = 0; i < 4; ++i) {
    int r = w * 32 + i * 8 + (lane >> 3);
    int cs = (lane & 7) ^ (r & 7);
    gload_lds16(g + (size_t)r * rowStrideElts + cs * 8, tile + r * 64 + (lane & 7) * 8);
  }
}

// ---------- convert / transpose ----------
__global__ __launch_bounds__(256) void cvt_f32_bf16(const float* __restrict__ in,
                                                    u16* __restrict__ out, int n4) {
  int i = blockIdx.x * 256 + threadIdx.x;
  if (i < n4) {
    float4 f = reinterpret_cast<const float4*>(in)[i];
    ushort4 o;
    o.x = f2b(f.x); o.y = f2b(f.y); o.z = f2b(f.z); o.w = f2b(f.w);
    reinterpret_cast<ushort4*>(out)[i] = o;
  }
}

// in[K][N] f32 -> out[N][K] bf16
__global__ __launch_bounds__(256) void transpose_cvt(const float* __restrict__ in,
                                                     u16* __restrict__ out, int K, int N) {
  __shared__ float t[32][33];
  int n0 = blockIdx.x * 32, k0 = blockIdx.y * 32;
  int tx = threadIdx.x & 31, ty = threadIdx.x >> 5;  // ty in 0..7
#pragma unroll
  for (int i = 0; i < 32; i += 8)
    t[ty + i][tx] = in[(size_t)(k0 + ty + i) * N + n0 + tx];
  __syncthreads();
#pragma unroll
  for (int i = 0; i < 32; i += 8)
    out[(size_t)(n0 + ty + i) * K + k0 + tx] = f2b(t[tx][ty + i]);
}

// ---------- GEMM1: qkv = x @ w_attn + b_attn, routed to q/k/vt ----------
// Q is pre-scaled by QSCL so attention scores exit MFMA in log2-domain.
__global__ __launch_bounds__(256) void gemm_qkv(const u16* __restrict__ xb,
                                                const u16* __restrict__ waT,
                                                const float* __restrict__ bias,
                                                u16* __restrict__ q, u16* __restrict__ kk,
                                                u16* __restrict__ vt) {
  __shared__ u16 lA[128 * 64];
  __shared__ u16 lB[128 * 64];
  int tid = threadIdx.x, lane = tid & 63, w = tid >> 6;
  int wr = w >> 1, wc = w & 1;
  int bm = blockIdx.x, bn = blockIdx.y;
  f32x4 acc[4][4] = {};
  const u16* gA = xb + (size_t)bm * 128 * 1024;
  const u16* gB = waT + (size_t)bn * 128 * 1024;
  for (int k0 = 0; k0 < 1024; k0 += 64) {
    stage128(gA + k0, 1024, lA, tid);
    stage128(gB + k0, 1024, lB, tid);
    __syncthreads();
#pragma unroll
    for (int s = 0; s < 2; ++s) {
      bf16x8 af[4], bfr[4];
#pragma unroll
      for (int mi = 0; mi < 4; ++mi)
        af[mi] = frag_read(lA, wr * 64 + mi * 16 + (lane & 15), (lane >> 4) + s * 4);
#pragma unroll
      for (int ni = 0; ni < 4; ++ni)
        bfr[ni] = frag_read(lB, wc * 64 + ni * 16 + (lane & 15), (lane >> 4) + s * 4);
#pragma unroll
      for (int mi = 0; mi < 4; ++mi)
#pragma unroll
        for (int ni = 0; ni < 4; ++ni)
          acc[mi][ni] = MFMA16(af[mi], bfr[ni], acc[mi][ni]);
    }
    __syncthreads();
  }
  int m0 = bm * 128 + wr * 64;
  int n0 = bn * 128 + wc * 64;
#pragma unroll
  for (int ni = 0; ni < 4; ++ni) {
    int col = n0 + ni * 16 + (lane & 15);
    float bv = bias[col];
    int part = col >> 10;
    int cin = col & 1023;
    int h = cin >> 6, d = cin & 63;
    float fct = (part == 0) ? QSCL : 1.0f;
#pragma unroll
    for (int mi = 0; mi < 4; ++mi) {
#pragma unroll
      for (int j = 0; j < 4; ++j) {
        int row = m0 + mi * 16 + (lane >> 4) * 4 + j;
        int b = row >> 11, t = row & 2047;
        u16 hv = f2b((acc[mi][ni][j] + bv) * fct);
        if (part == 0)
          q[(((size_t)(b * 16 + h) * 2048 + t) << 6) + d] = hv;
        else if (part == 1)
          kk[(((size_t)(b * 16 + h) * 2048 + t) << 6) + d] = hv;
        else
          vt[(((size_t)(b * 16 + h) << 6) + d) * 2048 + t] = hv;  // V pre-transposed [D][T]
      }
    }
  }
}

// ---------- GEMM2: out = att @ w_proj + b_proj (f32 out) ----------
__global__ __launch_bounds__(256) void gemm_proj(const u16* __restrict__ att,
                                                 const u16* __restrict__ wpT,
                                                 const float* __restrict__ bias,
                                                 float* __restrict__ out) {
  __shared__ u16 lA[128 * 64];
  __shared__ u16 lB[128 * 64];
  int tid = threadIdx.x, lane = tid & 63, w = tid >> 6;
  int wr = w >> 1, wc = w & 1;
  int bm = blockIdx.x, bn = blockIdx.y;
  f32x4 acc[4][4] = {};
  const u16* gA = att + (size_t)bm * 128 * 1024;
  const u16* gB = wpT + (size_t)bn * 128 * 1024;
  for (int k0 = 0; k0 < 1024; k0 += 64) {
    stage128(gA + k0, 1024, lA, tid);
    stage128(gB + k0, 1024, lB, tid);
    __syncthreads();
#pragma unroll
    for (int s = 0; s < 2; ++s) {
      bf16x8 af[4], bfr[4];
#pragma unroll
      for (int mi = 0; mi < 4; ++mi)
        af[mi] = frag_read(lA, wr * 64 + mi * 16 + (lane & 15), (lane >> 4) + s * 4);
#pragma unroll
      for (int ni = 0; ni < 4; ++ni)
        bfr[ni] = frag_read(lB, wc * 64 + ni * 16 + (lane & 15), (lane >> 4) + s * 4);
#pragma unroll
      for (int mi = 0; mi < 4; ++mi)
#pragma unroll
        for (int ni = 0; ni < 4; ++ni)
          acc[mi][ni] = MFMA16(af[mi], bfr[ni], acc[mi][ni]);
    }
    __syncthreads();
  }
  int m0 = bm * 128 + wr * 64;
  int n0 = bn * 128 + wc * 64;
#pragma unroll
  for (int ni = 0; ni < 4; ++ni) {
    int col = n0 + ni * 16 + (lane & 15);
    float bv = bias[col];
#pragma unroll
    for (int mi = 0; mi < 4; ++mi)
#pragma unroll
      for (int j = 0; j < 4; ++j) {
        int row = m0 + mi * 16 + (lane >> 4) * 4 + j;
        out[(size_t)row * 1024 + col] = acc[mi][ni][j] + bv;
      }
  }
}

// ---------- flash attention, swapped-operand + in-register P ----------
// S^T = mfma(K_frag, Q_frag): lane (ln,g) owns q-column ln, k = 16kc+4g+j.
// P^T B-fragments for PV are built IN REGISTERS: pack P pairs to dwords,
// then permlane32_swap + shfl_xor16 redistribute among the 4 lane-groups
// of each q-column (no LDS round-trip, no wave_barrier, no bank conflicts).
// m is row-uniform (rescale path reduces across groups); l is kept as
// per-lane partials and reduced once in the epilogue.
// Causal pairing: block (bh,y) handles q-tiles y and 31-y (33 tiles each).

__device__ __forceinline__ void stage_kv(const u16* kb, const u16* vb, int kt,
                                         u16* lK, u16* lV, int tid) {
  int lane = tid & 63, w = tid >> 6;
#pragma unroll
  for (int i = 0; i < 2; ++i) {
    int r = w * 16 + i * 8 + (lane >> 3);
    int cs = (lane & 7) ^ (r & 7);
    gload_lds16(kb + (size_t)(kt * 64 + r) * 64 + cs * 8, lK + r * 64 + (lane & 7) * 8);
    gload_lds16(vb + (size_t)r * 2048 + kt * 64 + cs * 8, lV + r * 64 + (lane & 7) * 8);
  }
}

// Redistribute two kc-pairs of packed P dwords into one B-fragment.
// (a0,a1) = dwords of kc-even, (b0,b1) = dwords of kc-odd.
__device__ __forceinline__ bf16x8 pdist(u32 a0, u32 a1, u32 b0, u32 b1, bool odd) {
  intx2 r0 = __builtin_amdgcn_permlane32_swap((int)a0, (int)b0, false, false);
  intx2 r1 = __builtin_amdgcn_permlane32_swap((int)a1, (int)b1, false, false);
  u32 x0 = __shfl_xor((u32)r0[1], 16, 64);  // swz16(B'_0)
  u32 x1 = __shfl_xor((u32)r1[1], 16, 64);  // swz16(B'_1)
  u32 y0 = __shfl_xor((u32)r0[0], 16, 64);  // swz16(A'_0)
  u32 y1 = __shfl_xor((u32)r1[0], 16, 64);  // swz16(A'_1)
  u32x4 f;
  f[0] = odd ? x0 : (u32)r0[0];
  f[1] = odd ? x1 : (u32)r1[0];
  f[2] = odd ? (u32)r0[1] : y0;
  f[3] = odd ? (u32)r1[1] : y1;
  return __builtin_bit_cast(bf16x8, f);
}

__global__ __launch_bounds__(256, 4) void attn_fwd(const u16* __restrict__ q,
                                                   const u16* __restrict__ kk,
                                                   const u16* __restrict__ vt,
                                                   u16* __restrict__ att) {
  __shared__ u16 lK[2][64 * 64];
  __shared__ u16 lV[2][64 * 64];
  int tid = threadIdx.x, lane = tid & 63, w = tid >> 6;
  int ln = lane & 15, g = lane >> 4;
  int gh = g >> 1, gl = g & 1;
  bool godd = (g & 1) != 0;
  int bh = blockIdx.x;
  int qtA = blockIdx.y;   // 0..15
  int qtB = 31 - qtA;     // 16..31
  const u16* qb = q + (size_t)bh * 2048 * 64;
  const u16* kb = kk + (size_t)bh * 2048 * 64;
  const u16* vb = vt + (size_t)bh * 64 * 2048;
  int q0A = qtA * 64 + w * 16;
  int q0B = qtB * 64 + w * 16;

  bf16x8 aqA[2], aqB[2];
  {
    const u16* pa = qb + (size_t)(q0A + ln) * 64 + g * 8;
    const u16* pb = qb + (size_t)(q0B + ln) * 64 + g * 8;
    aqA[0] = *reinterpret_cast<const bf16x8*>(pa);
    aqA[1] = *reinterpret_cast<const bf16x8*>(pa + 32);
    aqB[0] = *reinterpret_cast<const bf16x8*>(pb);
    aqB[1] = *reinterpret_cast<const bf16x8*>(pb + 32);
  }

  float mA = -1e30f, lA = 0.f, mB = -1e30f, lB = 0.f;
  f32x4 oA[4] = {}, oB[4] = {};

  // softmax for one state; emits the two P^T B-fragments in registers
  auto softmax_state = [&](f32x4* sf, float& m_r, float& l_r, f32x4* o,
                           bool domask, int k0, int qg,
                           bf16x8& pf0, bf16x8& pf1) {
    if (domask) {
#pragma unroll
      for (int kc = 0; kc < 4; ++kc)
#pragma unroll
        for (int j = 0; j < 4; ++j)
          if (k0 + kc * 16 + g * 4 + j > qg) sf[kc][j] = -1e30f;
    }
    // in-lane max over this lane's 16 values
    f32x4 m4;
#pragma unroll
    for (int j = 0; j < 4; ++j)
      m4[j] = fmaxf(fmaxf(sf[0][j], sf[1][j]), fmaxf(sf[2][j], sf[3][j]));
    float mxl = fmaxf(fmaxf(m4[0], m4[1]), fmaxf(m4[2], m4[3]));
    if (!__all(mxl - m_r <= 8.f)) {  // defer-max: rescale only on big growth
      float mx = fmaxf(mxl, __shfl_xor(mxl, 16, 64));
      mx = fmaxf(mx, __shfl_xor(mx, 32, 64));
      mx = fmaxf(m_r, mx);
      float sc = __builtin_amdgcn_exp2f(m_r - mx);
      m_r = mx;
      l_r *= sc;
#pragma unroll
      for (int dc = 0; dc < 4; ++dc) o[dc] *= sc;
    }
    u32 d0[4], d1[4];
    float rs = 0.f;
#pragma unroll
    for (int kc = 0; kc < 4; ++kc) {
      u16x4 v4;
#pragma unroll
      for (int j = 0; j < 4; ++j) {
        float p = __builtin_amdgcn_exp2f(sf[kc][j] - m_r);
        rs += p;
        v4[j] = f2b(p);
      }
      u32x2 dd = __builtin_bit_cast(u32x2, v4);
      d0[kc] = dd[0];
      d1[kc] = dd[1];
    }
    l_r += rs;  // per-lane partial; reduced across groups in epilogue
    pf0 = pdist(d0[0], d1[0], d0[1], d1[1], godd);
    pf1 = pdist(d0[2], d1[2], d0[3], d1[3], godd);
  };

  stage_kv(kb, vb, 0, &lK[0][0], &lV[0][0], tid);

  for (int kt = 0; kt <= qtB; ++kt) {
    int cur = kt & 1;
    __syncthreads();  // tile kt landed; previous compute done
    if (kt < qtB) stage_kv(kb, vb, kt + 1, &lK[cur ^ 1][0], &lV[cur ^ 1][0], tid);
    const u16* Kt = &lK[cur][0];
    const u16* Vt = &lV[cur][0];
    bool doA = (kt <= qtA);

    // QK^T both states, K-fragments shared
    f32x4 sB[4], sA[4];
    __builtin_amdgcn_s_setprio(1);
#pragma unroll
    for (int kc = 0; kc < 4; ++kc) {
      f32x4 zB = {}, zA = {};
#pragma unroll
      for (int s = 0; s < 2; ++s) {
        bf16x8 kf = frag_read(Kt, kc * 16 + ln, g + 4 * s);
        zB = MFMA16(kf, aqB[s], zB);
        if (doA) zA = MFMA16(kf, aqA[s], zA);
      }
      sB[kc] = zB;
      sA[kc] = zA;
    }
    __builtin_amdgcn_s_setprio(0);

    bf16x8 pB0, pB1, pA0, pA1;
    softmax_state(sB, mB, lB, oB, kt == qtB, kt * 64, q0B + ln, pB0, pB1);
    if (doA) softmax_state(sA, mA, lA, oA, kt == qtA, kt * 64, q0A + ln, pA0, pA1);

    // fused PV: V-fragments shared across both states
    __builtin_amdgcn_s_setprio(1);
#pragma unroll
    for (int dc = 0; dc < 4; ++dc) {
      bf16x8 v0 = frag_read(Vt, dc * 16 + ln, g);
      bf16x8 v1 = frag_read(Vt, dc * 16 + ln, g + 4);
      oB[dc] = MFMA16(v0, pB0, oB[dc]);
      oB[dc] = MFMA16(v1, pB1, oB[dc]);
      if (doA) {
        oA[dc] = MFMA16(v0, pA0, oA[dc]);
        oA[dc] = MFMA16(v1, pA1, oA[dc]);
      }
    }
    __builtin_amdgcn_s_setprio(0);
  }

  // epilogue: reduce l across groups; transpose O^T -> O via lK[0] scratch
  __syncthreads();  // everyone done with K/V LDS
  u16* lPw = &lK[0][0] + w * 1024;  // 16 rows x 64 u16 per wave
  int prow = ln * 128;
  int xorq = (ln & 7) << 4;
  int b = bh >> 4, h = bh & 15;
  auto epi = [&](const f32x4* o, float l_r, int q0w) {
    float lt = l_r + __shfl_xor(l_r, 16, 64);
    lt += __shfl_xor(lt, 32, 64);
    float inv = __builtin_amdgcn_rcpf(lt);
#pragma unroll
    for (int dc = 0; dc < 4; ++dc) {
      u16x4 v4;
#pragma unroll
      for (int j = 0; j < 4; ++j) v4[j] = f2b(o[dc][j] * inv);
      // O^T row d = 16*dc + 4*g + j, col q=ln  -> store at lPw[q][d]
      *reinterpret_cast<u16x4*>(reinterpret_cast<char*>(lPw) + prow +
                                ((((dc << 1) + gh) << 4) ^ xorq) + gl * 8) = v4;
    }
    asm volatile("s_waitcnt lgkmcnt(0)" ::: "memory");
    __builtin_amdgcn_sched_barrier(0);
    __builtin_amdgcn_wave_barrier();
    bf16x8 r0 = frag_read(lPw, ln, g);
    bf16x8 r1 = frag_read(lPw, ln, g + 4);
    __builtin_amdgcn_sched_barrier(0);
    int t = q0w + ln;
    u16* dst = att + (size_t)(b * 2048 + t) * 1024 + h * 64;
    *reinterpret_cast<bf16x8*>(dst + g * 8) = r0;
    *reinterpret_cast<bf16x8*>(dst + 32 + g * 8) = r1;
  };
  epi(oB, lB, q0B);
  epi(oA, lA, q0A);
}

extern "C" void kernel_launch(void* const* d_in, const int* in_sizes, int n_in,
                              void* d_out, int out_size, void* d_ws, size_t ws_size,
                              hipStream_t stream) {
  const float* x = (const float*)d_in[0];
  const float* w_attn = (const float*)d_in[1];
  const float* b_attn = (const float*)d_in[2];
  const float* w_proj = (const float*)d_in[3];
  const float* b_proj = (const float*)d_in[4];
  float* out = (float*)d_out;

  // workspace (u16 units): xb 8.39M (aliased by att after gemm_qkv),
  // waT 3.15M, wpT 1.05M, vt 8.39M  => ~42 MB total
  u16* ws = (u16*)d_ws;
  u16* xb = ws;
  u16* waT = xb + 8388608;
  u16* wpT = waT + 3145728;
  u16* vtx = wpT + 1048576;
  u16* att = xb;  // alias: xb dead after gemm_qkv
  // q/k live in d_out (33.5MB) as scratch; overwritten by gemm_proj at the end
  u16* qx = (u16*)d_out;
  u16* kx = qx + 8388608;

  cvt_f32_bf16<<<8192, 256, 0, stream>>>(x, xb, 2097152);
  transpose_cvt<<<dim3(96, 32), 256, 0, stream>>>(w_attn, waT, 1024, 3072);
  transpose_cvt<<<dim3(32, 32), 256, 0, stream>>>(w_proj, wpT, 1024, 1024);
  gemm_qkv<<<dim3(64, 24), 256, 0, stream>>>(xb, waT, b_attn, qx, kx, vtx);
  attn_fwd<<<dim3(64, 16), 256, 0, stream>>>(qx, kx, vtx, att);
  gemm_proj<<<dim3(64, 8), 256, 0, stream>>>(att, wpT, b_proj, out);
}

// Round 5
// 203.446 us; speedup vs baseline: 1.3174x; 1.0280x over previous
//
#include <hip/hip_runtime.h>
#include <hip/hip_bf16.h>

typedef unsigned short u16;
typedef unsigned int u32;
typedef __bf16 bf16_t;
typedef bf16_t bf16x8 __attribute__((ext_vector_type(8)));
typedef float f32x4 __attribute__((ext_vector_type(4)));
typedef u16 u16x4 __attribute__((ext_vector_type(4)));
typedef u32 u32x2 __attribute__((ext_vector_type(2)));
typedef u32 u32x4 __attribute__((ext_vector_type(4)));
typedef int intx2 __attribute__((ext_vector_type(2)));

#define MFMA16(a, b, c) __builtin_amdgcn_mfma_f32_16x16x32_bf16((a), (b), (c), 0, 0, 0)

// softmax scale folded into Q: 1/sqrt(64) * log2(e)
#define QSCL 0.18033688011112042f

__device__ __forceinline__ u16 f2b(float f) {
  bf16_t h = (bf16_t)f;
  return __builtin_bit_cast(u16, h);
}

__device__ __forceinline__ void gload_lds16(const void* src, void* dst) {
  __builtin_amdgcn_global_load_lds(
      (const __attribute__((address_space(1))) void*)src,
      (__attribute__((address_space(3))) void*)dst, 16, 0, 0);
}

// Read one 16B MFMA fragment from a swizzled LDS tile with 64-bf16 (128B) rows.
// Swizzle: 16B chunk c of row r is stored at chunk c ^ (r & 7).
__device__ __forceinline__ bf16x8 frag_read(const u16* tile, int row, int kchunk) {
  int off = row * 128 + ((kchunk ^ (row & 7)) << 4);
  return *reinterpret_cast<const bf16x8*>(reinterpret_cast<const char*>(tile) + off);
}

// Stage a 128-row x 64-bf16 tile (16KB) global->LDS, pre-swizzled global source
// so LDS dest stays linear (base + lane*16). 4 waves x 4 instrs, 8 rows each.
__device__ __forceinline__ void stage128(const u16* g, int rowStrideElts, u16* tile, int tid) {
  int lane = tid & 63, w = tid >> 6;
#pragma unroll
  for (int i = 0; i < 4; ++i) {
    int r = w * 32 + i * 8 + (lane >> 3);
    int cs = (lane & 7) ^ (r & 7);
    gload_lds16(g + (size_t)r * rowStrideElts + cs * 8, tile + r * 64 + (lane & 7) * 8);
  }
}

// ---------- convert / transpose ----------
__global__ __launch_bounds__(256) void cvt_f32_bf16(const float* __restrict__ in,
                                                    u16* __restrict__ out, int n4) {
  int i = blockIdx.x * 256 + threadIdx.x;
  if (i < n4) {
    float4 f = reinterpret_cast<const float4*>(in)[i];
    ushort4 o;
    o.x = f2b(f.x); o.y = f2b(f.y); o.z = f2b(f.z); o.w = f2b(f.w);
    reinterpret_cast<ushort4*>(out)[i] = o;
  }
}

// in[K][N] f32 -> out[N][K] bf16
__global__ __launch_bounds__(256) void transpose_cvt(const float* __restrict__ in,
                                                     u16* __restrict__ out, int K, int N) {
  __shared__ float t[32][33];
  int n0 = blockIdx.x * 32, k0 = blockIdx.y * 32;
  int tx = threadIdx.x & 31, ty = threadIdx.x >> 5;  // ty in 0..7
#pragma unroll
  for (int i = 0; i < 32; i += 8)
    t[ty + i][tx] = in[(size_t)(k0 + ty + i) * N + n0 + tx];
  __syncthreads();
#pragma unroll
  for (int i = 0; i < 32; i += 8)
    out[(size_t)(n0 + ty + i) * K + k0 + tx] = f2b(t[tx][ty + i]);
}

// ---------- GEMM1: qkv = x @ w_attn + b_attn, routed to q/k/vt ----------
// Q is pre-scaled by QSCL so attention scores exit MFMA in log2-domain.
__global__ __launch_bounds__(256) void gemm_qkv(const u16* __restrict__ xb,
                                                const u16* __restrict__ waT,
                                                const float* __restrict__ bias,
                                                u16* __restrict__ q, u16* __restrict__ kk,
                                                u16* __restrict__ vt) {
  __shared__ u16 lA[128 * 64];
  __shared__ u16 lB[128 * 64];
  int tid = threadIdx.x, lane = tid & 63, w = tid >> 6;
  int wr = w >> 1, wc = w & 1;
  int bm = blockIdx.x, bn = blockIdx.y;
  f32x4 acc[4][4] = {};
  const u16* gA = xb + (size_t)bm * 128 * 1024;
  const u16* gB = waT + (size_t)bn * 128 * 1024;
  for (int k0 = 0; k0 < 1024; k0 += 64) {
    stage128(gA + k0, 1024, lA, tid);
    stage128(gB + k0, 1024, lB, tid);
    __syncthreads();
#pragma unroll
    for (int s = 0; s < 2; ++s) {
      bf16x8 af[4], bfr[4];
#pragma unroll
      for (int mi = 0; mi < 4; ++mi)
        af[mi] = frag_read(lA, wr * 64 + mi * 16 + (lane & 15), (lane >> 4) + s * 4);
#pragma unroll
      for (int ni = 0; ni < 4; ++ni)
        bfr[ni] = frag_read(lB, wc * 64 + ni * 16 + (lane & 15), (lane >> 4) + s * 4);
#pragma unroll
      for (int mi = 0; mi < 4; ++mi)
#pragma unroll
        for (int ni = 0; ni < 4; ++ni)
          acc[mi][ni] = MFMA16(af[mi], bfr[ni], acc[mi][ni]);
    }
    __syncthreads();
  }
  int m0 = bm * 128 + wr * 64;
  int n0 = bn * 128 + wc * 64;
#pragma unroll
  for (int ni = 0; ni < 4; ++ni) {
    int col = n0 + ni * 16 + (lane & 15);
    float bv = bias[col];
    int part = col >> 10;
    int cin = col & 1023;
    int h = cin >> 6, d = cin & 63;
    float fct = (part == 0) ? QSCL : 1.0f;
#pragma unroll
    for (int mi = 0; mi < 4; ++mi) {
#pragma unroll
      for (int j = 0; j < 4; ++j) {
        int row = m0 + mi * 16 + (lane >> 4) * 4 + j;
        int b = row >> 11, t = row & 2047;
        u16 hv = f2b((acc[mi][ni][j] + bv) * fct);
        if (part == 0)
          q[(((size_t)(b * 16 + h) * 2048 + t) << 6) + d] = hv;
        else if (part == 1)
          kk[(((size_t)(b * 16 + h) * 2048 + t) << 6) + d] = hv;
        else
          vt[(((size_t)(b * 16 + h) << 6) + d) * 2048 + t] = hv;  // V pre-transposed [D][T]
      }
    }
  }
}

// ---------- GEMM2: out = att @ w_proj + b_proj (f32 out) ----------
__global__ __launch_bounds__(256) void gemm_proj(const u16* __restrict__ att,
                                                 const u16* __restrict__ wpT,
                                                 const float* __restrict__ bias,
                                                 float* __restrict__ out) {
  __shared__ u16 lA[128 * 64];
  __shared__ u16 lB[128 * 64];
  int tid = threadIdx.x, lane = tid & 63, w = tid >> 6;
  int wr = w >> 1, wc = w & 1;
  int bm = blockIdx.x, bn = blockIdx.y;
  f32x4 acc[4][4] = {};
  const u16* gA = att + (size_t)bm * 128 * 1024;
  const u16* gB = wpT + (size_t)bn * 128 * 1024;
  for (int k0 = 0; k0 < 1024; k0 += 64) {
    stage128(gA + k0, 1024, lA, tid);
    stage128(gB + k0, 1024, lB, tid);
    __syncthreads();
#pragma unroll
    for (int s = 0; s < 2; ++s) {
      bf16x8 af[4], bfr[4];
#pragma unroll
      for (int mi = 0; mi < 4; ++mi)
        af[mi] = frag_read(lA, wr * 64 + mi * 16 + (lane & 15), (lane >> 4) + s * 4);
#pragma unroll
      for (int ni = 0; ni < 4; ++ni)
        bfr[ni] = frag_read(lB, wc * 64 + ni * 16 + (lane & 15), (lane >> 4) + s * 4);
#pragma unroll
      for (int mi = 0; mi < 4; ++mi)
#pragma unroll
        for (int ni = 0; ni < 4; ++ni)
          acc[mi][ni] = MFMA16(af[mi], bfr[ni], acc[mi][ni]);
    }
    __syncthreads();
  }
  int m0 = bm * 128 + wr * 64;
  int n0 = bn * 128 + wc * 64;
#pragma unroll
  for (int ni = 0; ni < 4; ++ni) {
    int col = n0 + ni * 16 + (lane & 15);
    float bv = bias[col];
#pragma unroll
    for (int mi = 0; mi < 4; ++mi)
#pragma unroll
      for (int j = 0; j < 4; ++j) {
        int row = m0 + mi * 16 + (lane >> 4) * 4 + j;
        out[(size_t)row * 1024 + col] = acc[mi][ni][j] + bv;
      }
  }
}

// ---------- flash attention: swapped-operand, in-register P, counted vmcnt ----------
// S^T = mfma(K_frag, Q_frag); P^T B-fragments built in registers
// (permlane32_swap + shfl_xor16). Triple-buffered K/V staging with raw
// s_barrier + s_waitcnt vmcnt(4): tile kt's loads are issued two compute
// phases ahead; vmcnt never drains to 0 in the steady-state loop (T3/T4).
// Causal pairing: block (bh,y) handles q-tiles y and 31-y (33 tiles each).

__device__ __forceinline__ void stage_kv(const u16* kb, const u16* vb, int kt,
                                         u16* lK, u16* lV, int tid) {
  int lane = tid & 63, w = tid >> 6;
#pragma unroll
  for (int i = 0; i < 2; ++i) {
    int r = w * 16 + i * 8 + (lane >> 3);
    int cs = (lane & 7) ^ (r & 7);
    gload_lds16(kb + (size_t)(kt * 64 + r) * 64 + cs * 8, lK + r * 64 + (lane & 7) * 8);
    gload_lds16(vb + (size_t)r * 2048 + kt * 64 + cs * 8, lV + r * 64 + (lane & 7) * 8);
  }
}

// Redistribute two kc-pairs of packed P dwords into one B-fragment.
// (a0,a1) = dwords of kc-even, (b0,b1) = dwords of kc-odd.
__device__ __forceinline__ bf16x8 pdist(u32 a0, u32 a1, u32 b0, u32 b1, bool odd) {
  intx2 r0 = __builtin_amdgcn_permlane32_swap((int)a0, (int)b0, false, false);
  intx2 r1 = __builtin_amdgcn_permlane32_swap((int)a1, (int)b1, false, false);
  u32 x0 = __shfl_xor((u32)r0[1], 16, 64);  // swz16(B'_0)
  u32 x1 = __shfl_xor((u32)r1[1], 16, 64);  // swz16(B'_1)
  u32 y0 = __shfl_xor((u32)r0[0], 16, 64);  // swz16(A'_0)
  u32 y1 = __shfl_xor((u32)r1[0], 16, 64);  // swz16(A'_1)
  u32x4 f;
  f[0] = odd ? x0 : (u32)r0[0];
  f[1] = odd ? x1 : (u32)r1[0];
  f[2] = odd ? (u32)r0[1] : y0;
  f[3] = odd ? (u32)r1[1] : y1;
  return __builtin_bit_cast(bf16x8, f);
}

__global__ __launch_bounds__(256, 3) void attn_fwd(const u16* __restrict__ q,
                                                   const u16* __restrict__ kk,
                                                   const u16* __restrict__ vt,
                                                   u16* __restrict__ att) {
  __shared__ u16 lK[3][64 * 64];
  __shared__ u16 lV[3][64 * 64];
  int tid = threadIdx.x, lane = tid & 63, w = tid >> 6;
  int ln = lane & 15, g = lane >> 4;
  int gh = g >> 1, gl = g & 1;
  bool godd = (g & 1) != 0;
  int bh = blockIdx.x;
  int qtA = blockIdx.y;   // 0..15
  int qtB = 31 - qtA;     // 16..31
  const u16* qb = q + (size_t)bh * 2048 * 64;
  const u16* kb = kk + (size_t)bh * 2048 * 64;
  const u16* vb = vt + (size_t)bh * 64 * 2048;
  int q0A = qtA * 64 + w * 16;
  int q0B = qtB * 64 + w * 16;

  bf16x8 aqA[2], aqB[2];
  {
    const u16* pa = qb + (size_t)(q0A + ln) * 64 + g * 8;
    const u16* pb = qb + (size_t)(q0B + ln) * 64 + g * 8;
    aqA[0] = *reinterpret_cast<const bf16x8*>(pa);
    aqA[1] = *reinterpret_cast<const bf16x8*>(pa + 32);
    aqB[0] = *reinterpret_cast<const bf16x8*>(pb);
    aqB[1] = *reinterpret_cast<const bf16x8*>(pb + 32);
  }

  float mA = -1e30f, lA = 0.f, mB = -1e30f, lB = 0.f;
  f32x4 oA[4] = {}, oB[4] = {};

  // softmax for one state; emits the two P^T B-fragments in registers
  auto softmax_state = [&](f32x4* sf, float& m_r, float& l_r, f32x4* o,
                           bool domask, int k0, int qg,
                           bf16x8& pf0, bf16x8& pf1) {
    if (domask) {
#pragma unroll
      for (int kc = 0; kc < 4; ++kc)
#pragma unroll
        for (int j = 0; j < 4; ++j)
          if (k0 + kc * 16 + g * 4 + j > qg) sf[kc][j] = -1e30f;
    }
    // in-lane max over this lane's 16 values
    f32x4 m4;
#pragma unroll
    for (int j = 0; j < 4; ++j)
      m4[j] = fmaxf(fmaxf(sf[0][j], sf[1][j]), fmaxf(sf[2][j], sf[3][j]));
    float mxl = fmaxf(fmaxf(m4[0], m4[1]), fmaxf(m4[2], m4[3]));
    if (!__all(mxl - m_r <= 8.f)) {  // defer-max: rescale only on big growth
      float mx = fmaxf(mxl, __shfl_xor(mxl, 16, 64));
      mx = fmaxf(mx, __shfl_xor(mx, 32, 64));
      mx = fmaxf(m_r, mx);
      float sc = __builtin_amdgcn_exp2f(m_r - mx);
      m_r = mx;
      l_r *= sc;
#pragma unroll
      for (int dc = 0; dc < 4; ++dc) o[dc] *= sc;
    }
    u32 d0[4], d1[4];
    float rs = 0.f;
#pragma unroll
    for (int kc = 0; kc < 4; ++kc) {
      u16x4 v4;
#pragma unroll
      for (int j = 0; j < 4; ++j) {
        float p = __builtin_amdgcn_exp2f(sf[kc][j] - m_r);
        rs += p;
        v4[j] = f2b(p);
      }
      u32x2 dd = __builtin_bit_cast(u32x2, v4);
      d0[kc] = dd[0];
      d1[kc] = dd[1];
    }
    l_r += rs;  // per-lane partial; reduced across groups in epilogue
    pf0 = pdist(d0[0], d1[0], d0[1], d1[1], godd);
    pf1 = pdist(d0[2], d1[2], d0[3], d1[3], godd);
  };

  // prologue: two tiles in flight before the loop (qtB >= 16 so both exist)
  stage_kv(kb, vb, 0, &lK[0][0], &lV[0][0], tid);
  stage_kv(kb, vb, 1, &lK[1][0], &lV[1][0], tid);

  for (int kt = 0; kt <= qtB; ++kt) {
    // wait for tile kt (leave tile kt+1's 4 loads in flight), then sync
    if (kt < qtB) {
      asm volatile("s_waitcnt vmcnt(4)" ::: "memory");
    } else {
      asm volatile("s_waitcnt vmcnt(0)" ::: "memory");
    }
    __builtin_amdgcn_s_barrier();
    // prefetch tile kt+2 into the buffer last read at compute(kt-1)
    if (kt + 2 <= qtB) {
      int nb = kt + 2 - ((kt + 2) >= 3 ? 3 : 0);
      nb = (kt + 2) % 3;
      stage_kv(kb, vb, kt + 2, &lK[nb][0], &lV[nb][0], tid);
    }
    int cur = kt % 3;
    const u16* Kt = &lK[cur][0];
    const u16* Vt = &lV[cur][0];
    bool doA = (kt <= qtA);

    // QK^T both states, K-fragments shared
    f32x4 sB[4], sA[4];
    __builtin_amdgcn_s_setprio(1);
#pragma unroll
    for (int kc = 0; kc < 4; ++kc) {
      f32x4 zB = {}, zA = {};
#pragma unroll
      for (int s = 0; s < 2; ++s) {
        bf16x8 kf = frag_read(Kt, kc * 16 + ln, g + 4 * s);
        zB = MFMA16(kf, aqB[s], zB);
        if (doA) zA = MFMA16(kf, aqA[s], zA);
      }
      sB[kc] = zB;
      sA[kc] = zA;
    }
    __builtin_amdgcn_s_setprio(0);

    // V-fragment register cache (shared by both states; loads overlap SM_B)
    bf16x8 vf0[4], vf1[4];
#pragma unroll
    for (int dc = 0; dc < 4; ++dc) {
      vf0[dc] = frag_read(Vt, dc * 16 + ln, g);
      vf1[dc] = frag_read(Vt, dc * 16 + ln, g + 4);
    }

    bf16x8 pB0, pB1, pA0, pA1;
    softmax_state(sB, mB, lB, oB, kt == qtB, kt * 64, q0B + ln, pB0, pB1);
    __builtin_amdgcn_s_setprio(1);
#pragma unroll
    for (int dc = 0; dc < 4; ++dc) {
      oB[dc] = MFMA16(vf0[dc], pB0, oB[dc]);
      oB[dc] = MFMA16(vf1[dc], pB1, oB[dc]);
    }
    __builtin_amdgcn_s_setprio(0);
    if (doA) {
      // SM_A's VALU chain overlaps PV_B's MFMAs (independent)
      softmax_state(sA, mA, lA, oA, kt == qtA, kt * 64, q0A + ln, pA0, pA1);
      __builtin_amdgcn_s_setprio(1);
#pragma unroll
      for (int dc = 0; dc < 4; ++dc) {
        oA[dc] = MFMA16(vf0[dc], pA0, oA[dc]);
        oA[dc] = MFMA16(vf1[dc], pA1, oA[dc]);
      }
      __builtin_amdgcn_s_setprio(0);
    }
  }

  // epilogue: reduce l across groups; transpose O^T -> O via lK[0] scratch
  __syncthreads();  // everyone done with K/V LDS
  u16* lPw = &lK[0][0] + w * 1024;  // 16 rows x 64 u16 per wave
  int prow = ln * 128;
  int xorq = (ln & 7) << 4;
  int b = bh >> 4, h = bh & 15;
  auto epi = [&](const f32x4* o, float l_r, int q0w) {
    float lt = l_r + __shfl_xor(l_r, 16, 64);
    lt += __shfl_xor(lt, 32, 64);
    float inv = __builtin_amdgcn_rcpf(lt);
#pragma unroll
    for (int dc = 0; dc < 4; ++dc) {
      u16x4 v4;
#pragma unroll
      for (int j = 0; j < 4; ++j) v4[j] = f2b(o[dc][j] * inv);
      // O^T row d = 16*dc + 4*g + j, col q=ln  -> store at lPw[q][d]
      *reinterpret_cast<u16x4*>(reinterpret_cast<char*>(lPw) + prow +
                                ((((dc << 1) + gh) << 4) ^ xorq) + gl * 8) = v4;
    }
    asm volatile("s_waitcnt lgkmcnt(0)" ::: "memory");
    __builtin_amdgcn_sched_barrier(0);
    __builtin_amdgcn_wave_barrier();
    bf16x8 r0 = frag_read(lPw, ln, g);
    bf16x8 r1 = frag_read(lPw, ln, g + 4);
    __builtin_amdgcn_sched_barrier(0);
    int t = q0w + ln;
    u16* dst = att + (size_t)(b * 2048 + t) * 1024 + h * 64;
    *reinterpret_cast<bf16x8*>(dst + g * 8) = r0;
    *reinterpret_cast<bf16x8*>(dst + 32 + g * 8) = r1;
  };
  epi(oB, lB, q0B);
  epi(oA, lA, q0A);
}

extern "C" void kernel_launch(void* const* d_in, const int* in_sizes, int n_in,
                              void* d_out, int out_size, void* d_ws, size_t ws_size,
                              hipStream_t stream) {
  const float* x = (const float*)d_in[0];
  const float* w_attn = (const float*)d_in[1];
  const float* b_attn = (const float*)d_in[2];
  const float* w_proj = (const float*)d_in[3];
  const float* b_proj = (const float*)d_in[4];
  float* out = (float*)d_out;

  // workspace (u16 units): xb 8.39M (aliased by att after gemm_qkv),
  // waT 3.15M, wpT 1.05M, vt 8.39M  => ~42 MB total
  u16* ws = (u16*)d_ws;
  u16* xb = ws;
  u16* waT = xb + 8388608;
  u16* wpT = waT + 3145728;
  u16* vtx = wpT + 1048576;
  u16* att = xb;  // alias: xb dead after gemm_qkv
  // q/k live in d_out (33.5MB) as scratch; overwritten by gemm_proj at the end
  u16* qx = (u16*)d_out;
  u16* kx = qx + 8388608;

  cvt_f32_bf16<<<8192, 256, 0, stream>>>(x, xb, 2097152);
  transpose_cvt<<<dim3(96, 32), 256, 0, stream>>>(w_attn, waT, 1024, 3072);
  transpose_cvt<<<dim3(32, 32), 256, 0, stream>>>(w_proj, wpT, 1024, 1024);
  gemm_qkv<<<dim3(64, 24), 256, 0, stream>>>(xb, waT, b_attn, qx, kx, vtx);
  attn_fwd<<<dim3(64, 16), 256, 0, stream>>>(qx, kx, vtx, att);
  gemm_proj<<<dim3(64, 8), 256, 0, stream>>>(att, wpT, b_proj, out);
}